// Round 8
// baseline (117.246 us; speedup 1.0000x reference)
//
#include <hip/hip_runtime.h>
#include <math.h>
#include <stdint.h>

#define HH 512
#define WW 512
#define BB 64
#define NP 13860
#define WPR 16                       // 32-bit words per image row
#define IMG_WORDS (BB * HH * WPR)    // 2 MB bit-image for all batches

struct GaussW { float g[9]; };

__device__ __forceinline__ int reflect_idx(int i) {
    if (i < 0) i = -i;
    if (i > 511) i = 1022 - i;
    return i;
}

// ----------------------------------------------------------------- zero ----
__global__ __launch_bounds__(256)
void zero_kernel(uint4* __restrict__ p) {
    p[blockIdx.x * 256 + threadIdx.x] = make_uint4(0u, 0u, 0u, 0u);
}

// ---------------------------------------------------------------- splat ----
// One thread = one (point, batch). Identical fp semantics to passing r4-r7.
__global__ __launch_bounds__(256)
void splat_kernel(const float* __restrict__ V,
                  const float* __restrict__ P,
                  const float* __restrict__ pts,
                  unsigned int* __restrict__ gbm) {
    __shared__ float VP[4][4];
    const int b = blockIdx.y;
    const int t = threadIdx.x;
    if (t < 16) {
        const int i = t >> 2, k = t & 3;
        const float* Pb = P + b * 16;
        const float* Vb = V + b * 16;
        float a = __fmul_rn(Pb[i*4+0], Vb[0*4+k]);
        a = __fmaf_rn(Pb[i*4+1], Vb[1*4+k], a);
        a = __fmaf_rn(Pb[i*4+2], Vb[2*4+k], a);
        a = __fmaf_rn(Pb[i*4+3], Vb[3*4+k], a);
        VP[i][k] = a;
    }
    __syncthreads();
    const int n = blockIdx.x * 256 + t;
    if (n >= NP) return;
    const float4 p = ((const float4*)pts)[n];
    float tp0, tp1, tp3;
    {
        float a = __fmul_rn(p.x, VP[0][0]);
        a = __fmaf_rn(p.y, VP[0][1], a);
        a = __fmaf_rn(p.z, VP[0][2], a);
        a = __fmaf_rn(p.w, VP[0][3], a);
        tp0 = a;
    }
    {
        float a = __fmul_rn(p.x, VP[1][0]);
        a = __fmaf_rn(p.y, VP[1][1], a);
        a = __fmaf_rn(p.z, VP[1][2], a);
        a = __fmaf_rn(p.w, VP[1][3], a);
        tp1 = a;
    }
    {
        float a = __fmul_rn(p.x, VP[3][0]);
        a = __fmaf_rn(p.y, VP[3][1], a);
        a = __fmaf_rn(p.z, VP[3][2], a);
        a = __fmaf_rn(p.w, VP[3][3], a);
        tp3 = a;
    }
    const float w = tp3;
    const float x = (w != 0.f) ? (tp0 / w) : tp0;
    const float y = (w != 0.f) ? (tp1 / w) : tp1;
    const float sxf = rintf(__fmul_rn(__fmul_rn(__fadd_rn(x, 1.f), 0.5f), 512.f));
    const float tmp = __fmul_rn(__fadd_rn(y, 1.f), 0.5f);
    const float syf = rintf(__fmul_rn(__fsub_rn(1.f, tmp), 512.f));
    int sx, sy;
    if (sxf >= 0.f && sxf < 512.f && syf >= 0.f && syf < 512.f) {
        sx = (int)sxf; sy = (int)syf;
    } else {
        sx = 511; sy = 511;   // JAX: flat=-1 wraps to last pixel, not dropped
    }
    atomicOr(&gbm[(b * HH + sy) * WPR + (sx >> 5)], 1u << (sx & 31));
}

// ------------------- tile kernel: dilate + blur + threshold + store --------
// Uniformity fast paths at block and thread level; exact LUT path for the
// mixed transition ring. Slow path fp semantics identical to r7 (passing).
__global__ __launch_bounds__(256)
void tile_kernel(const unsigned int* __restrict__ gbm,
                 float* __restrict__ out, GaussW gw) {
    __shared__ unsigned int bm[80][4];
    __shared__ unsigned int hd[80][4];
    __shared__ unsigned int dl[72][4];
    __shared__ float lut[512];
    __shared__ unsigned int orAcc, andAcc;

    const int b  = blockIdx.z;
    const int x0 = blockIdx.x * 64;
    const int y0 = blockIdx.y * 64;
    const int tx = threadIdx.x;          // 0..15 -> 4-col group
    const int ty = threadIdx.y;          // 0..15 -> 4-row group
    const int tid = ty * 16 + tx;

    const int R0  = (y0 - 8 > 0) ? y0 - 8 : 0;
    const int R1  = (y0 + 71 < 511) ? y0 + 71 : 511;
    const int W0  = (x0 == 0) ? 0 : (x0 / 32 - 1);
    const int RD0 = (y0 - 4 > 0) ? y0 - 4 : 0;
    const int RD1 = (y0 + 67 < 511) ? y0 + 67 : 511;
    const int NR  = R1 - R0 + 1;

    if (tid == 0) { orAcc = 0u; andAcc = 0xFFFFFFFFu; }

    // phase A: load bitmap halo + build vertical-blur LUT (exact fma chain)
    const unsigned int* gb = gbm + b * HH * WPR;
    for (int e = tid; e < 80 * 4; e += 256) {
        const int r = e >> 2, j = e & 3;
        unsigned int v = 0u;
        if (r < NR && W0 + j < WPR) v = gb[(R0 + r) * WPR + (W0 + j)];
        bm[r][j] = v;
    }
    for (int e = tid; e < 512; e += 256) {
        float acc = 0.f;
#pragma unroll
        for (int dy = 0; dy < 9; ++dy) {
            const float val = ((e >> dy) & 1) ? 255.f : 0.f;
            acc = __fmaf_rn(gw.g[dy], val, acc);
        }
        lut[e] = acc;
    }
    __syncthreads();

    // phase B1: horizontal dilation (+-4)
    for (int e = tid; e < NR * 4; e += 256) {
        const int r = e >> 2, j = e & 3;
        const unsigned int w  = bm[r][j];
        const unsigned int wl = (j > 0) ? bm[r][j-1] : 0u;
        const unsigned int wr = (j < 3) ? bm[r][j+1] : 0u;
        unsigned int h = w;
#pragma unroll
        for (int k = 1; k <= 4; ++k) {
            h |= (w << k) | (wl >> (32 - k));
            h |= (w >> k) | (wr << (32 - k));
        }
        hd[r][j] = h;
    }
    __syncthreads();

    // phase B2: vertical dilation (+-4) + block uniformity accumulators
    const int ND = RD1 - RD0 + 1;
    for (int e = tid; e < ND * 4; e += 256) {
        const int r = RD0 + (e >> 2), j = e & 3;
        const int lo = (r - 4 > 0) ? r - 4 : 0;
        const int hi = (r + 4 < 511) ? r + 4 : 511;
        unsigned int acc = 0u;
        for (int rr = lo; rr <= hi; ++rr) acc |= hd[rr - R0][j];
        dl[r - RD0][j] = acc;
        atomicOr(&orAcc, acc);
        atomicAnd(&andAcc, acc);
    }
    __syncthreads();

    const int c0 = 4 * tx;
    const unsigned int bOr = orAcc, bAnd = andAcc;

    float4 mq;
    float* mp = (float*)&mq;

    // block-level fast path: whole halo uniform
    if (bOr == 0u || bAnd == 0xFFFFFFFFu) {
        const float m = (bOr == 0u) ? 0.f : 1.f;
        mq = make_float4(m, m, m, m);
#pragma unroll
        for (int r = 0; r < 4; ++r) {
            const int yq = y0 + 4 * ty + r, xq = x0 + c0;
            float* o = out + ((size_t)(b * 3) * HH + yq) * WW + xq;
            *(float4*)(o)                       = mq;
            *(float4*)(o + (size_t)HH * WW)     = mq;
            *(float4*)(o + (size_t)2 * HH * WW) = mq;
        }
        return;
    }

    // 12 dl-row indices (cheap when no row reflection)
    int ridx[12];
    const int rbase = y0 + 4 * ty - 4;
    if (rbase >= 0 && rbase + 11 <= 511) {
#pragma unroll
        for (int k = 0; k < 12; ++k) ridx[k] = rbase + k - RD0;
    } else {
#pragma unroll
        for (int k = 0; k < 12; ++k) ridx[k] = reflect_idx(rbase + k) - RD0;
    }

    const int colA = reflect_idx(x0 + c0 - 4);
    const int colB = reflect_idx(x0 + c0 + 7);
    const int wA = (colA >> 5) - W0;
    const int wB = (colB >> 5) - W0;

    unsigned int w_lo[12], w_hi[12];
#pragma unroll
    for (int k = 0; k < 12; ++k) {
        w_lo[k] = dl[ridx[k]][wA];
        w_hi[k] = dl[ridx[k]][wB];
    }

    const bool colReflect = (x0 == 0 && tx == 0) || (x0 == 448 && tx == 15);

    float vs[4][12];
    bool uniform = false;
    float um = 0.f;

    if (!colReflect) {
        // contiguous 12-col window: one funnel shift per row
        const int sh = colA & 31;
        unsigned int f[12], fOr = 0u, fAnd = 0xFFFu;
#pragma unroll
        for (int k = 0; k < 12; ++k) {
            const unsigned long long cat =
                (((unsigned long long)w_hi[k]) << 32) | (unsigned long long)w_lo[k];
            f[k] = (unsigned int)(cat >> sh) & 0xFFFu;
            fOr |= f[k]; fAnd &= f[k];
        }
        if (fOr == 0u)        { uniform = true; um = 0.f; }
        else if (fAnd == 0xFFFu) { uniform = true; um = 1.f; }
        else {
            // transpose 12x12 bits: v12[j] bit k = f[k] bit j
#pragma unroll
            for (int j = 0; j < 12; ++j) {
                unsigned int v12 = 0u;
#pragma unroll
                for (int k = 0; k < 12; ++k)
                    v12 |= ((f[k] >> j) & 1u) << k;
#pragma unroll
                for (int r = 0; r < 4; ++r)
                    vs[r][j] = lut[(v12 >> r) & 0x1FFu];
            }
        }
    } else {
        // rare reflected-column threads: exact r7 per-col path
#pragma unroll
        for (int j = 0; j < 12; ++j) {
            const int col = reflect_idx(x0 + c0 - 4 + j);
            const int sel = (col >> 5) - W0;
            const int shc = col & 31;
            unsigned int v12 = 0u;
#pragma unroll
            for (int k = 0; k < 12; ++k) {
                const unsigned int wk = (sel == wB) ? w_hi[k] : w_lo[k];
                v12 |= ((wk >> shc) & 1u) << k;
            }
#pragma unroll
            for (int r = 0; r < 4; ++r)
                vs[r][j] = lut[(v12 >> r) & 0x1FFu];
        }
    }

    if (uniform) {
        mq = make_float4(um, um, um, um);
#pragma unroll
        for (int r = 0; r < 4; ++r) {
            const int yq = y0 + 4 * ty + r, xq = x0 + c0;
            float* o = out + ((size_t)(b * 3) * HH + yq) * WW + xq;
            *(float4*)(o)                       = mq;
            *(float4*)(o + (size_t)HH * WW)     = mq;
            *(float4*)(o + (size_t)2 * HH * WW) = mq;
        }
        return;
    }

    // horizontal 9-tap (ascending dx fma chain) + threshold + store
#pragma unroll
    for (int r = 0; r < 4; ++r) {
#pragma unroll
        for (int q = 0; q < 4; ++q) {
            float acc = 0.f;
#pragma unroll
            for (int dx = 0; dx < 9; ++dx)
                acc = __fmaf_rn(gw.g[dx], vs[r][q + dx], acc);
            mp[q] = (rintf(acc) > 100.f) ? 1.f : 0.f;
        }
        const int yq = y0 + 4 * ty + r, xq = x0 + c0;
        float* o = out + ((size_t)(b * 3) * HH + yq) * WW + xq;
        *(float4*)(o)                       = mq;
        *(float4*)(o + (size_t)HH * WW)     = mq;
        *(float4*)(o + (size_t)2 * HH * WW) = mq;
    }
}

// ---------------------------------------------------------------- launch ---
extern "C" void kernel_launch(void* const* d_in, const int* in_sizes, int n_in,
                              void* d_out, int out_size, void* d_ws, size_t ws_size,
                              hipStream_t stream) {
    const float* V   = (const float*)d_in[0];
    const float* P   = (const float*)d_in[1];
    const float* pts = (const float*)d_in[2];
    float* out = (float*)d_out;
    unsigned int* gbm = (unsigned int*)d_ws;   // 2 MB bit-image

    // Gaussian weights, replicating numpy f64 computation incl. pairwise sum
    const double sigma = 0.3 * ((9 - 1) * 0.5 - 1.0) + 0.8;
    double gd[9];
    for (int i = 0; i < 9; ++i) {
        const double t = ((double)i - 4.0) / sigma;
        gd[i] = exp(-0.5 * (t * t));
    }
    double s = ((gd[0] + gd[1]) + (gd[2] + gd[3])) + ((gd[4] + gd[5]) + (gd[6] + gd[7]));
    s += gd[8];
    GaussW gw;
    for (int i = 0; i < 9; ++i) gw.g[i] = (float)(gd[i] / s);

    zero_kernel<<<IMG_WORDS / 4 / 256, 256, 0, stream>>>((uint4*)gbm);
    splat_kernel<<<dim3((NP + 255) / 256, BB), 256, 0, stream>>>(V, P, pts, gbm);
    tile_kernel<<<dim3(8, 8, BB), dim3(16, 16), 0, stream>>>(gbm, out, gw);
}

// Round 9
// 90.444 us; speedup vs baseline: 1.2963x; 1.2963x over previous
//
#include <hip/hip_runtime.h>
#include <math.h>
#include <stdint.h>

#define HH 512
#define WW 512
#define BB 64
#define NP 13860
#define WPR 16                       // 32-bit words per image row
#define IMG_WORDS (BB * HH * WPR)    // 2 MB bit-image for all batches

struct GaussW { float g[9]; };

__device__ __forceinline__ int reflect_idx(int i) {
    if (i < 0) i = -i;
    if (i > 511) i = 1022 - i;
    return i;
}

// ----------------------------------------------------------------- zero ----
__global__ __launch_bounds__(256)
void zero_kernel(uint4* __restrict__ p) {
    p[blockIdx.x * 256 + threadIdx.x] = make_uint4(0u, 0u, 0u, 0u);
}

// ---------------------------------------------------------------- splat ----
// One thread = one (point, batch). Identical fp semantics to passing r4-r8.
__global__ __launch_bounds__(256)
void splat_kernel(const float* __restrict__ V,
                  const float* __restrict__ P,
                  const float* __restrict__ pts,
                  unsigned int* __restrict__ gbm) {
    __shared__ float VP[4][4];
    const int b = blockIdx.y;
    const int t = threadIdx.x;
    if (t < 16) {
        const int i = t >> 2, k = t & 3;
        const float* Pb = P + b * 16;
        const float* Vb = V + b * 16;
        float a = __fmul_rn(Pb[i*4+0], Vb[0*4+k]);
        a = __fmaf_rn(Pb[i*4+1], Vb[1*4+k], a);
        a = __fmaf_rn(Pb[i*4+2], Vb[2*4+k], a);
        a = __fmaf_rn(Pb[i*4+3], Vb[3*4+k], a);
        VP[i][k] = a;
    }
    __syncthreads();
    const int n = blockIdx.x * 256 + t;
    if (n >= NP) return;
    const float4 p = ((const float4*)pts)[n];
    float tp0, tp1, tp3;
    {
        float a = __fmul_rn(p.x, VP[0][0]);
        a = __fmaf_rn(p.y, VP[0][1], a);
        a = __fmaf_rn(p.z, VP[0][2], a);
        a = __fmaf_rn(p.w, VP[0][3], a);
        tp0 = a;
    }
    {
        float a = __fmul_rn(p.x, VP[1][0]);
        a = __fmaf_rn(p.y, VP[1][1], a);
        a = __fmaf_rn(p.z, VP[1][2], a);
        a = __fmaf_rn(p.w, VP[1][3], a);
        tp1 = a;
    }
    {
        float a = __fmul_rn(p.x, VP[3][0]);
        a = __fmaf_rn(p.y, VP[3][1], a);
        a = __fmaf_rn(p.z, VP[3][2], a);
        a = __fmaf_rn(p.w, VP[3][3], a);
        tp3 = a;
    }
    const float w = tp3;
    const float x = (w != 0.f) ? (tp0 / w) : tp0;
    const float y = (w != 0.f) ? (tp1 / w) : tp1;
    const float sxf = rintf(__fmul_rn(__fmul_rn(__fadd_rn(x, 1.f), 0.5f), 512.f));
    const float tmp = __fmul_rn(__fadd_rn(y, 1.f), 0.5f);
    const float syf = rintf(__fmul_rn(__fsub_rn(1.f, tmp), 512.f));
    int sx, sy;
    if (sxf >= 0.f && sxf < 512.f && syf >= 0.f && syf < 512.f) {
        sx = (int)sxf; sy = (int)syf;
    } else {
        sx = 511; sy = 511;   // JAX: flat=-1 wraps to last pixel, not dropped
    }
    atomicOr(&gbm[(b * HH + sy) * WPR + (sx >> 5)], 1u << (sx & 31));
}

// ------------------- tile kernel: dilate + blur + threshold + store --------
// Lean version of r7: low-VGPR streaming phase C/D, funnel-shift extraction,
// global-direct horizontal dilation (one less barrier, no bm LDS).
__global__ __launch_bounds__(256)
void tile_kernel(const unsigned int* __restrict__ gbm,
                 float* __restrict__ out, GaussW gw) {
    __shared__ unsigned int hd[80][4];   // horizontally dilated halo rows
    __shared__ unsigned int dl[72][4];   // fully dilated, rows RD0..RD1
    __shared__ float lut[512];           // vertical-blur LUT (exact fma chain)

    const int b  = blockIdx.z;
    const int x0 = blockIdx.x * 64;
    const int y0 = blockIdx.y * 64;
    const int tx = threadIdx.x;          // 0..15 -> 4-col group
    const int ty = threadIdx.y;          // 0..15 -> 4-row group
    const int tid = ty * 16 + tx;

    const int R0  = (y0 - 8 > 0) ? y0 - 8 : 0;
    const int R1  = (y0 + 71 < 511) ? y0 + 71 : 511;
    const int W0  = (x0 == 0) ? 0 : (x0 / 32 - 1);
    const int RD0 = (y0 - 4 > 0) ? y0 - 4 : 0;
    const int RD1 = (y0 + 67 < 511) ? y0 + 67 : 511;
    const int NR  = R1 - R0 + 1;

    // LUT build (pure VALU; overlaps the global loads below)
    for (int e = tid; e < 512; e += 256) {
        float acc = 0.f;
#pragma unroll
        for (int dy = 0; dy < 9; ++dy) {
            const float val = ((e >> dy) & 1) ? 255.f : 0.f;
            acc = __fmaf_rn(gw.g[dy], val, acc);
        }
        lut[e] = acc;
    }

    // phase B1: horizontal dilation (+-4), reading bitmap direct from global
    const unsigned int* gb = gbm + b * HH * WPR;
    for (int e = tid; e < NR * 4; e += 256) {
        const int r = e >> 2, j = e & 3;
        const int gr = R0 + r, gj = W0 + j;
        const unsigned int w  = (gj < WPR)              ? gb[gr * WPR + gj]     : 0u;
        const unsigned int wl = (gj > 0 && gj - 1 < WPR) ? gb[gr * WPR + gj - 1] : 0u;
        const unsigned int wr = (gj + 1 < WPR)           ? gb[gr * WPR + gj + 1] : 0u;
        unsigned int h = w;
#pragma unroll
        for (int k = 1; k <= 4; ++k) {
            h |= (w << k) | (wl >> (32 - k));
            h |= (w >> k) | (wr << (32 - k));
        }
        hd[r][j] = h;
    }
    __syncthreads();

    // phase B2: vertical dilation (+-4), clamped at image borders
    const int ND = RD1 - RD0 + 1;
    for (int e = tid; e < ND * 4; e += 256) {
        const int r = RD0 + (e >> 2), j = e & 3;
        const int lo = (r - 4 > 0) ? r - 4 : 0;
        const int hi = (r + 4 < 511) ? r + 4 : 511;
        unsigned int acc = 0u;
        for (int rr = lo; rr <= hi; ++rr) acc |= hd[rr - R0][j];
        dl[r - RD0][j] = acc;
    }
    __syncthreads();

    // phase C: build 12 column-patterns (v12) for this thread's 4x4 patch
    const int c0 = 4 * tx;
    int rrk[12];
    const int rbase = y0 + 4 * ty - 4;
#pragma unroll
    for (int k = 0; k < 12; ++k)
        rrk[k] = reflect_idx(rbase + k) - RD0;

    const int colA = reflect_idx(x0 + c0 - 4);
    const int colB = reflect_idx(x0 + c0 + 7);
    const int wA = (colA >> 5) - W0;
    const int wB = (colB >> 5) - W0;
    const bool colRef = (x0 == 0 && tx == 0) || (x0 == 448 && tx == 15);

    unsigned int v12[12];
    if (!colRef) {
        // contiguous 12-col window: one funnel shift per row, then transpose
        const int sh = colA & 31;
        unsigned int e12[12];
#pragma unroll
        for (int k = 0; k < 12; ++k) {
            const unsigned long long cat =
                (((unsigned long long)dl[rrk[k]][wB]) << 32) |
                (unsigned long long)dl[rrk[k]][wA];
            e12[k] = (unsigned int)(cat >> sh) & 0xFFFu;
        }
#pragma unroll
        for (int j = 0; j < 12; ++j) {
            unsigned int v = 0u;
#pragma unroll
            for (int k = 0; k < 12; ++k)
                v |= ((e12[k] >> j) & 1u) << k;
            v12[j] = v;
        }
    } else {
        // rare reflected-column lanes: exact per-column path (r7 semantics)
#pragma unroll
        for (int j = 0; j < 12; ++j) {
            const int col = reflect_idx(x0 + c0 - 4 + j);
            const int sel = (col >> 5) - W0;
            const int shc = col & 31;
            unsigned int v = 0u;
#pragma unroll
            for (int k = 0; k < 12; ++k)
                v |= ((dl[rrk[k]][sel] >> shc) & 1u) << k;
            v12[j] = v;
        }
    }

    // phase D: per output row -> LUT (vertical blur) + horizontal 9-tap +
    // threshold + 3-channel float4 store. Only 12 floats live at a time.
#pragma unroll
    for (int r = 0; r < 4; ++r) {
        float f[12];
#pragma unroll
        for (int j = 0; j < 12; ++j)
            f[j] = lut[(v12[j] >> r) & 0x1FFu];
        float4 mq;
        float* mp = (float*)&mq;
#pragma unroll
        for (int q = 0; q < 4; ++q) {
            float acc = 0.f;
#pragma unroll
            for (int dx = 0; dx < 9; ++dx)
                acc = __fmaf_rn(gw.g[dx], f[q + dx], acc);
            mp[q] = (rintf(acc) > 100.f) ? 1.f : 0.f;
        }
        const int yq = y0 + 4 * ty + r, xq = x0 + c0;
        float* o = out + ((size_t)(b * 3) * HH + yq) * WW + xq;
        *(float4*)(o)                       = mq;
        *(float4*)(o + (size_t)HH * WW)     = mq;
        *(float4*)(o + (size_t)2 * HH * WW) = mq;
    }
}

// ---------------------------------------------------------------- launch ---
extern "C" void kernel_launch(void* const* d_in, const int* in_sizes, int n_in,
                              void* d_out, int out_size, void* d_ws, size_t ws_size,
                              hipStream_t stream) {
    const float* V   = (const float*)d_in[0];
    const float* P   = (const float*)d_in[1];
    const float* pts = (const float*)d_in[2];
    float* out = (float*)d_out;
    unsigned int* gbm = (unsigned int*)d_ws;   // 2 MB bit-image

    // Gaussian weights, replicating numpy f64 computation incl. pairwise sum
    const double sigma = 0.3 * ((9 - 1) * 0.5 - 1.0) + 0.8;
    double gd[9];
    for (int i = 0; i < 9; ++i) {
        const double t = ((double)i - 4.0) / sigma;
        gd[i] = exp(-0.5 * (t * t));
    }
    double s = ((gd[0] + gd[1]) + (gd[2] + gd[3])) + ((gd[4] + gd[5]) + (gd[6] + gd[7]));
    s += gd[8];
    GaussW gw;
    for (int i = 0; i < 9; ++i) gw.g[i] = (float)(gd[i] / s);

    zero_kernel<<<IMG_WORDS / 4 / 256, 256, 0, stream>>>((uint4*)gbm);
    splat_kernel<<<dim3((NP + 255) / 256, BB), 256, 0, stream>>>(V, P, pts, gbm);
    tile_kernel<<<dim3(8, 8, BB), dim3(16, 16), 0, stream>>>(gbm, out, gw);
}